// Round 16
// baseline (3914.214 us; speedup 1.0000x reference)
//
#include <hip/hip_runtime.h>
#include <hip/hip_bf16.h>

#define Bd 64
#define Td 64
#define Sd 128
#define Hd 512
#define Ed 256
#define Vd 10000
#define NBLK 256

#define W0IH 0      // 6*768
#define W0HH 4608   // 6*512
#define W1IH 7680   // 6*512
#define W1HH 10752  // 6*512
#define WTOT 13824

typedef __attribute__((ext_vector_type(8))) short bf16x8;
typedef __attribute__((ext_vector_type(4))) float f32x4;

__device__ __forceinline__ float fast_tanh(float x) {
  float e = __expf(-2.0f * fabsf(x));
  float r = (1.0f - e) / (1.0f + e);
  return copysignf(r, x);
}
__device__ __forceinline__ float fast_sigmoid(float x) {
  return 1.0f / (1.0f + __expf(-x));
}
__device__ __forceinline__ float bf2f(unsigned short u) {
  return __uint_as_float(((unsigned int)u) << 16);
}
__device__ __forceinline__ void st_llc(float* p, float v) {
  __hip_atomic_store(p, v, __ATOMIC_RELAXED, __HIP_MEMORY_SCOPE_AGENT);
}
// k-quad state layout: element (k, b) lives at (k>>2)*256 + b*4 + (k&3)
__device__ __forceinline__ int q4(int k, int b) {
  return (k >> 2) * 256 + b * 4 + (k & 3);
}

// wbl2-free grid barrier (r12): relaxed arrive/go + single acquire inv.
__device__ __forceinline__ void gbar(int* arrive, int* go, int ep, int blk, int tid) {
  __syncthreads();
  if (tid == 0)
    __hip_atomic_store(&arrive[blk], ep, __ATOMIC_RELAXED, __HIP_MEMORY_SCOPE_AGENT);
  if (blk == 0) {
    if (tid < 64) {
      for (;;) {
        int a0 = __hip_atomic_load(&arrive[tid], __ATOMIC_RELAXED,
                                   __HIP_MEMORY_SCOPE_AGENT);
        int a1 = __hip_atomic_load(&arrive[tid + 64], __ATOMIC_RELAXED,
                                   __HIP_MEMORY_SCOPE_AGENT);
        int a2 = __hip_atomic_load(&arrive[tid + 128], __ATOMIC_RELAXED,
                                   __HIP_MEMORY_SCOPE_AGENT);
        int a3 = __hip_atomic_load(&arrive[tid + 192], __ATOMIC_RELAXED,
                                   __HIP_MEMORY_SCOPE_AGENT);
        if (a0 >= ep && a1 >= ep && a2 >= ep && a3 >= ep) break;
        __builtin_amdgcn_s_sleep(2);
      }
    }
    __syncthreads();
    if (tid == 0)
      __hip_atomic_store(go, ep, __ATOMIC_RELAXED, __HIP_MEMORY_SCOPE_AGENT);
  }
  if (tid == 0) {
    while (__hip_atomic_load(go, __ATOMIC_RELAXED, __HIP_MEMORY_SCOPE_AGENT) < ep) {
      __builtin_amdgcn_s_sleep(1);
    }
    __builtin_amdgcn_fence(__ATOMIC_ACQUIRE, "agent");
  }
  __syncthreads();
}

// fp32 tiled GEMM (kp prep). C[M,N] = A[M,K] @ W[N,K]^T, bf16 out.
__global__ void k_gemm_kp(const float* __restrict__ A, const float* __restrict__ W,
                          unsigned short* __restrict__ C, int M, int N, int K) {
  __shared__ __align__(16) float As[16][64];
  __shared__ __align__(16) float Ws[16][64];
  int m0 = blockIdx.x * 64, n0 = blockIdx.y * 64;
  int tid = threadIdx.x;
  int tx = tid & 15, ty = tid >> 4;
  float acc[4][4] = {};
  for (int k0 = 0; k0 < K; k0 += 16) {
#pragma unroll
    for (int i = 0; i < 4; i++) {
      int e = tid + i * 256;
      int r = e >> 4, c = e & 15;
      As[c][r] = A[(long)(m0 + r) * K + k0 + c];
      Ws[c][r] = W[(long)(n0 + r) * K + k0 + c];
    }
    __syncthreads();
#pragma unroll
    for (int k = 0; k < 16; k++) {
      float a_[4], w_[4];
#pragma unroll
      for (int i = 0; i < 4; i++) a_[i] = As[k][ty * 4 + i];
#pragma unroll
      for (int j = 0; j < 4; j++) w_[j] = Ws[k][tx * 4 + j];
#pragma unroll
      for (int i = 0; i < 4; i++)
#pragma unroll
        for (int j = 0; j < 4; j++) acc[i][j] += a_[i] * w_[j];
    }
    __syncthreads();
  }
#pragma unroll
  for (int i = 0; i < 4; i++)
#pragma unroll
    for (int j = 0; j < 4; j++) {
      __hip_bfloat16 h = __float2bfloat16(acc[i][j]);
      C[(long)(m0 + ty * 4 + i) * N + n0 + tx * 4 + j] = *(unsigned short*)&h;
    }
}

// embG[row][t*64+b] = sum_e Wih0[row][512+e] * emb[x[b][t]][e]   (fp32 GEMM)
// grid: (1536/64, Td), 256 threads
__global__ void k_embG(const int* __restrict__ x, const float* __restrict__ emb,
                       const float* __restrict__ Wih0, float* __restrict__ embG) {
  __shared__ __align__(16) float As[16][64];
  __shared__ __align__(16) float Bs[16][64];
  __shared__ int xs[64];
  int m0 = blockIdx.x * 64, t = blockIdx.y;
  int tid = threadIdx.x;
  int tx = tid & 15, ty = tid >> 4;
  if (tid < 64) xs[tid] = x[tid * Td + t];
  __syncthreads();
  float acc[4][4] = {};
  for (int k0 = 0; k0 < Ed; k0 += 16) {
#pragma unroll
    for (int i = 0; i < 4; i++) {
      int e = tid + i * 256;
      int r = e >> 4, c = e & 15;
      As[c][r] = Wih0[(size_t)(m0 + r) * 768 + 512 + k0 + c];
      Bs[c][r] = emb[(size_t)xs[r] * Ed + k0 + c];
    }
    __syncthreads();
#pragma unroll
    for (int k = 0; k < 16; k++) {
      float a_[4], b_[4];
#pragma unroll
      for (int i = 0; i < 4; i++) a_[i] = As[k][ty * 4 + i];
#pragma unroll
      for (int j = 0; j < 4; j++) b_[j] = Bs[k][tx * 4 + j];
#pragma unroll
      for (int i = 0; i < 4; i++)
#pragma unroll
        for (int j = 0; j < 4; j++) acc[i][j] += a_[i] * b_[j];
    }
    __syncthreads();
  }
#pragma unroll
  for (int i = 0; i < 4; i++)
#pragma unroll
    for (int j = 0; j < 4; j++)
      embG[(size_t)(m0 + ty * 4 + i) * 4096 + t * 64 + tx * 4 + j] = acc[i][j];
}

// bf16 MFMA logits GEMM
__global__ __launch_bounds__(256) void k_logits(
    const unsigned short* __restrict__ ysbf, const unsigned short* __restrict__ Wdbf,
    const float* __restrict__ bd, float* __restrict__ out, int N) {
  int m0 = blockIdx.x * 64, n0 = blockIdx.y * 64;
  int w = threadIdx.x >> 6, lane = threadIdx.x & 63;
  int row = lane & 15, kg = lane >> 4;
  int mw = m0 + w * 16;
  f32x4 acc[4] = {};
  const unsigned short* Arow = ysbf + (size_t)(mw + row) * 512 + kg * 8;
  for (int k0 = 0; k0 < 512; k0 += 32) {
    bf16x8 af = *(const bf16x8*)(Arow + k0);
#pragma unroll
    for (int nn = 0; nn < 4; nn++) {
      int ncol = n0 + nn * 16 + row;
      bf16x8 bfv = {};
      if (ncol < N) bfv = *(const bf16x8*)(Wdbf + (size_t)ncol * 512 + k0 + kg * 8);
      acc[nn] = __builtin_amdgcn_mfma_f32_16x16x32_bf16(af, bfv, acc[nn], 0, 0, 0);
    }
  }
#pragma unroll
  for (int nn = 0; nn < 4; nn++) {
    int ncol = n0 + nn * 16 + row;
    if (ncol < N) {
      float bv = bd[ncol];
#pragma unroll
      for (int r = 0; r < 4; r++) {
        int mm = mw + kg * 4 + r;
        int t_ = mm >> 6, b_ = mm & 63;
        out[((size_t)(b_ * Td + t_)) * N + ncol] = acc[nn][r] + bv;
      }
    }
  }
}

// elementwise f32 -> bf16 copy
__global__ void k_tobf(const float* __restrict__ src, unsigned short* __restrict__ dst,
                       long n) {
  long i = (long)blockIdx.x * 1024 + threadIdx.x;
  if (i < n) {
    __hip_bfloat16 h = __float2bfloat16(src[i]);
    dst[i] = *(unsigned short*)&h;
  }
}

// GRU cell phase, EIGHTH-split read-once: waves 0-7 ih k-eighths (6 rows, 64 k
// each), waves 8-15 hh k-eighths. State float4 loads; weights LDS broadcast.
// cell0's emb contribution comes precomputed from embG (3 scalar loads in
// combine). Combine (8 partials) + nonlinearity by threads 0-127.
template <bool C0>
__device__ __forceinline__ void cell_phase(
    int blk, int tid, int t, const float* __restrict__ aT,
    const float* __restrict__ embG, const float* __restrict__ hT,
    const float* wIH, const float* wHH, const float* __restrict__ bih,
    const float* __restrict__ bhh, const float* __restrict__ den,
    float* __restrict__ houtT, unsigned short* __restrict__ ysbf, float* scratch) {
  int lane = tid & 63;
  int w = tid >> 6;
  const int RIH = C0 ? 768 : 512;
  float* ps = scratch;  // [12 rows][8 eighths][64]
  {
    int strm = w >> 3, e8 = w & 7;
    const float* A = (strm == 0 ? aT : hT) + e8 * 16 * 256;  // 64 k = 16 quads
    float a[6] = {0.f, 0.f, 0.f, 0.f, 0.f, 0.f};
#pragma unroll
    for (int k4 = 0; k4 < 16; k4++) {
      float4 av = *(const float4*)&A[k4 * 256 + lane * 4];
#pragma unroll
      for (int r = 0; r < 6; r++) {
        const float* wr = (strm == 0 ? wIH + (size_t)r * RIH : wHH + (size_t)r * 512) +
                          e8 * 64 + k4 * 4;
        float4 w4 = *(const float4*)wr;
        a[r] += av.x * w4.x + av.y * w4.y + av.z * w4.z + av.w * w4.w;
      }
    }
    if (C0 && strm == 0) {
      float inv = 1.0f / den[lane];
#pragma unroll
      for (int r = 0; r < 6; r++) a[r] *= inv;
    }
    int base = strm * 6;
#pragma unroll
    for (int r = 0; r < 6; r++) ps[((base + r) * 8 + e8) * 64 + lane] = a[r];
  }
  __syncthreads();
  if (tid < 128) {
    int jl = tid >> 6, b = tid & 63;
    int j = blk * 2 + jl;
#define RD(R)                                                                   \
  (ps[((R)*8 + 0) * 64 + b] + ps[((R)*8 + 1) * 64 + b] +                        \
   ps[((R)*8 + 2) * 64 + b] + ps[((R)*8 + 3) * 64 + b] +                        \
   ps[((R)*8 + 4) * 64 + b] + ps[((R)*8 + 5) * 64 + b] +                        \
   ps[((R)*8 + 6) * 64 + b] + ps[((R)*8 + 7) * 64 + b])
    float ir = RD(0 + jl);
    float iz = RD(2 + jl);
    float in = RD(4 + jl);
    if (C0) {
      int col = t * 64 + b;
      ir += embG[(size_t)j * 4096 + col];
      iz += embG[(size_t)(512 + j) * 4096 + col];
      in += embG[(size_t)(1024 + j) * 4096 + col];
    }
    float hr = RD(6 + jl);
    float hz = RD(8 + jl);
    float hn_ = RD(10 + jl);
#undef RD
    float r = fast_sigmoid(ir + hr + bih[j] + bhh[j]);
    float z = fast_sigmoid(iz + hz + bih[Hd + j] + bhh[Hd + j]);
    float n = fast_tanh(in + bih[2 * Hd + j] + r * (hn_ + bhh[2 * Hd + j]));
    float hp = hT[q4(j, b)];
    float out = (1.f - z) * n + z * hp;
    st_llc(&houtT[q4(j, b)], out);
    if (!C0) {
      __hip_bfloat16 hb = __float2bfloat16(out);
      ysbf[((size_t)t * 64 + b) * 512 + j] = *(unsigned short*)&hb;
    }
  }
}

__global__ __launch_bounds__(1024, 1) void k_decoder(
    const float* __restrict__ h0_in, const int* __restrict__ vlen,
    const float* __restrict__ Wq, const float* __restrict__ wvp,
    const float* __restrict__ Wih0, const float* __restrict__ Whh0,
    const float* __restrict__ bih0, const float* __restrict__ bhh0,
    const float* __restrict__ Wih1, const float* __restrict__ Whh1,
    const float* __restrict__ bih1, const float* __restrict__ bhh1,
    const unsigned short* __restrict__ kpbf, const unsigned short* __restrict__ encbf,
    const float* __restrict__ embG, int* bar, float* qpN, float* ctxT,
    float* den, float* h0TA, float* h0TB, float* h1TA, float* h1TB,
    unsigned short* ysbf) {
  __shared__ __align__(16) float wLDS[WTOT];               // 55296 B
  __shared__ __align__(16) float WqL[1024];                // 4096 B
  __shared__ __align__(16) unsigned short kpL[32 * 512];   // 32768 B
  __shared__ __align__(16) unsigned short encL[32 * 512];  // 32768 B
  __shared__ __align__(16) float scratch[6144];            // 24576 B (union)
  int blk = blockIdx.x, tid = threadIdx.x;
  int lane = tid & 63;
  int w = tid >> 6;
  int battn = blk >> 2, q = blk & 3;
  int* arrive = bar;
  int* go = bar + NBLK;
  int ep = 0;

  // ---- one-time staging ----
  {
    int j0 = blk * 2;
#pragma unroll
    for (int rr = 0; rr < 6; rr++) {
      int g = rr >> 1, jl = rr & 1;
      int row = g * Hd + j0 + jl;
      const float* s0 = Wih0 + (size_t)row * 768;
      for (int k = tid; k < 768; k += 1024) wLDS[W0IH + rr * 768 + k] = s0[k];
      const float* s1 = Whh0 + (size_t)row * Hd;
      for (int k = tid; k < Hd; k += 1024) wLDS[W0HH + rr * 512 + k] = s1[k];
      const float* s2 = Wih1 + (size_t)row * Hd;
      for (int k = tid; k < Hd; k += 1024) wLDS[W1IH + rr * 512 + k] = s2[k];
      const float* s3 = Whh1 + (size_t)row * Hd;
      for (int k = tid; k < Hd; k += 1024) wLDS[W1HH + rr * 512 + k] = s3[k];
    }
    WqL[tid] = Wq[(size_t)(blk * 2 + (tid >> 9)) * Hd + (tid & 511)];
    const uint4* ksrc = (const uint4*)(kpbf + ((size_t)battn * Sd + q * 32) * Hd);
    const uint4* esrc = (const uint4*)(encbf + ((size_t)battn * Sd + q * 32) * Hd);
    uint4* kdst = (uint4*)kpL;
    uint4* edst = (uint4*)encL;
    for (int i = tid; i < 2048; i += 1024) {
      kdst[i] = ksrc[i];
      edst[i] = esrc[i];
    }
  }
  float wvr[8];
#pragma unroll
  for (int i = 0; i < 8; i++) wvr[i] = wvp[lane * 8 + i];

  // init: h0 transpose into k-quad buffers; zero ctxT/den
  if (blk < Bd) {
    int b = blk;
    for (int k = tid; k < Hd; k += 1024) {
      st_llc(&h0TA[q4(k, b)], h0_in[(0 * Bd + b) * Hd + k]);
      st_llc(&h1TA[q4(k, b)], h0_in[(1 * Bd + b) * Hd + k]);
    }
  }
  if (tid < 128) st_llc(&ctxT[blk * 128 + tid], 0.f);
  if (blk < Bd && tid == 128) st_llc(&den[blk], 0.f);
  gbar(arrive, go, ++ep, blk, tid);

  for (int t = 0; t < Td; t++) {
    const float* h0prev = (t & 1) ? h0TB : h0TA;
    float* h0next = (t & 1) ? h0TA : h0TB;
    const float* h1prev = (t & 1) ? h1TB : h1TA;
    float* h1next = (t & 1) ? h1TA : h1TB;

    // ---- P0: qproj, 256 blocks x 2 rows; h1 read as k-quad float4 ----
    {
      int rl = w >> 3, ks = w & 7;
      const float* qrow = &WqL[rl * 512 + ks * 64];
      const float* hp4 = h1prev + (ks * 16) * 256 + lane * 4;
      float acc = 0.f;
#pragma unroll
      for (int kk = 0; kk < 64; kk += 4) {
        float4 hv = *(const float4*)&hp4[(kk >> 2) * 256];
        acc += hv.x * qrow[kk] + hv.y * qrow[kk + 1] + hv.z * qrow[kk + 2] +
               hv.w * qrow[kk + 3];
      }
      scratch[w * 64 + lane] = acc;
      __syncthreads();
      if (tid < 128) {
        int rl2 = tid >> 6, b = tid & 63;
        float s = 0.f;
#pragma unroll
        for (int qq = 0; qq < 8; qq++) s += scratch[(rl2 * 8 + qq) * 64 + b];
        st_llc(&qpN[(size_t)b * 512 + blk * 2 + rl2], s);
      }
    }
    gbar(arrive, go, ++ep, blk, tid);

    // ---- P1: attention partial (b=battn, 32 s-rows from LDS) ----
    {
      int b = battn;
      float* sc = scratch;  // [32]
      float qv[8];
      const float* qb = qpN + (size_t)b * 512 + lane * 8;
#pragma unroll
      for (int i = 0; i < 8; i++) qv[i] = qb[i];
      int vl = vlen[b];
#pragma unroll
      for (int si = 0; si < 2; si++) {
        int sl = w * 2 + si;
        uint4 kw = *(const uint4*)&kpL[sl * 512 + lane * 8];
        float f0 = __uint_as_float(kw.x << 16);
        float f1 = __uint_as_float(kw.x & 0xffff0000u);
        float f2 = __uint_as_float(kw.y << 16);
        float f3 = __uint_as_float(kw.y & 0xffff0000u);
        float f4 = __uint_as_float(kw.z << 16);
        float f5 = __uint_as_float(kw.z & 0xffff0000u);
        float f6 = __uint_as_float(kw.w << 16);
        float f7 = __uint_as_float(kw.w & 0xffff0000u);
        float acc = wvr[0] * fast_tanh(qv[0] + f0) + wvr[1] * fast_tanh(qv[1] + f1) +
                    wvr[2] * fast_tanh(qv[2] + f2) + wvr[3] * fast_tanh(qv[3] + f3) +
                    wvr[4] * fast_tanh(qv[4] + f4) + wvr[5] * fast_tanh(qv[5] + f5) +
                    wvr[6] * fast_tanh(qv[6] + f6) + wvr[7] * fast_tanh(qv[7] + f7);
#pragma unroll
        for (int off = 1; off < 64; off <<= 1) acc += __shfl_xor(acc, off);
        if (lane == 0) {
          int s = q * 32 + sl;
          sc[sl] = (s < vl) ? __expf(acc) : 0.f;  // no-max softmax: |score|<=~9
        }
      }
      __syncthreads();
      if (tid < 32) {
        float p2 = sc[tid];
#pragma unroll
        for (int off = 1; off < 32; off <<= 1) p2 += __shfl_xor(p2, off, 32);
        if (tid == 0) atomicAdd(&den[b], p2);
      }
      if (tid < 512) {
        float acc = 0.f;
#pragma unroll 8
        for (int s = 0; s < 32; s++) acc += sc[s] * bf2f(encL[s * 512 + tid]);
        atomicAdd(&ctxT[q4(tid, b)], acc);
      }
    }
    gbar(arrive, go, ++ep, blk, tid);

    // ---- P2: GRU cell 0 ----
    cell_phase<true>(blk, tid, t, ctxT, embG, h0prev, wLDS + W0IH, wLDS + W0HH,
                     bih0, bhh0, den, h0next, nullptr, scratch);
    gbar(arrive, go, ++ep, blk, tid);

    // ---- P3: zero ctxT/den + GRU cell 1 ----
    if (tid < 128) st_llc(&ctxT[blk * 128 + tid], 0.f);
    if (blk < Bd && tid == 128) st_llc(&den[blk], 0.f);
    cell_phase<false>(blk, tid, t, h0next, nullptr, h1prev, wLDS + W1IH,
                      wLDS + W1HH, bih1, bhh1, nullptr, h1next, ysbf, scratch);
    gbar(arrive, go, ++ep, blk, tid);
  }
}

extern "C" void kernel_launch(void* const* d_in, const int* in_sizes, int n_in,
                              void* d_out, int out_size, void* d_ws, size_t ws_size,
                              hipStream_t stream) {
  const int* x = (const int*)d_in[0];
  const float* enc = (const float*)d_in[1];
  const float* h0 = (const float*)d_in[2];
  const int* vlen = (const int*)d_in[3];
  const float* emb = (const float*)d_in[4];
  const float* Wq = (const float*)d_in[5];
  const float* Wk = (const float*)d_in[6];
  const float* wv = (const float*)d_in[7];
  const float* W_ih0 = (const float*)d_in[8];
  const float* W_hh0 = (const float*)d_in[9];
  const float* b_ih0 = (const float*)d_in[10];
  const float* b_hh0 = (const float*)d_in[11];
  const float* W_ih1 = (const float*)d_in[12];
  const float* W_hh1 = (const float*)d_in[13];
  const float* b_ih1 = (const float*)d_in[14];
  const float* b_hh1 = (const float*)d_in[15];
  const float* Wd = (const float*)d_in[16];
  const float* bd = (const float*)d_in[17];
  float* out = (float*)d_out;

  char* p = (char*)d_ws;
  int* bar = (int*)p;
  p += 2048;
  unsigned short* kpbf = (unsigned short*)p;   // B*S*H bf16
  p += (size_t)Bd * Sd * Hd * 2;
  unsigned short* encbf = (unsigned short*)p;  // B*S*H bf16
  p += (size_t)Bd * Sd * Hd * 2;
  unsigned short* Wdbf = (unsigned short*)p;   // V*H bf16
  p += (size_t)Vd * Hd * 2;
  unsigned short* ysbf = (unsigned short*)p;   // T*B*H bf16
  p += (size_t)Td * Bd * Hd * 2;
  float* embG = (float*)p;  // 1536 * 4096 f32 = 25.2 MB
  p += (size_t)1536 * 4096 * 4;
  float* qpN = (float*)p;   p += (size_t)Bd * Hd * 4;
  float* ctxT = (float*)p;  p += (size_t)Hd * Bd * 4;
  float* den = (float*)p;   p += 256;
  float* h0TA = (float*)p;  p += (size_t)Hd * Bd * 4;
  float* h0TB = (float*)p;  p += (size_t)Hd * Bd * 4;
  float* h1TA = (float*)p;  p += (size_t)Hd * Bd * 4;
  float* h1TB = (float*)p;

  hipMemsetAsync(bar, 0, 2048, stream);

  // kp = enc @ Wk^T -> bf16
  k_gemm_kp<<<dim3(128, 8), 256, 0, stream>>>(enc, Wk, kpbf, Bd * Sd, Hd, Hd);
  // enc, Wd -> bf16
  long nenc = (long)Bd * Sd * Hd;
  k_tobf<<<(nenc + 1023) / 1024, 1024, 0, stream>>>(enc, encbf, nenc);
  long nwd = (long)Vd * Hd;
  k_tobf<<<(nwd + 1023) / 1024, 1024, 0, stream>>>(Wd, Wdbf, nwd);
  // embG = Wih0[:,512:768] @ emb[x]^T  (precomputed emb gate contribution)
  k_embG<<<dim3(24, Td), 256, 0, stream>>>(x, emb, W_ih0, embG);
  // fused 64-step decoder (4 barriers/step)
  k_decoder<<<NBLK, 1024, 0, stream>>>(h0, vlen, Wq, wv, W_ih0, W_hh0, b_ih0,
                                       b_hh0, W_ih1, W_hh1, b_ih1, b_hh1, kpbf,
                                       encbf, embG, bar, qpN, ctxT, den, h0TA,
                                       h0TB, h1TA, h1TB, ysbf);
  // logits: bf16 MFMA GEMM
  k_logits<<<dim3(64, 157), 256, 0, stream>>>(ysbf, Wdbf, bd, out, Vd);
}

// Round 17
// 3897.977 us; speedup vs baseline: 1.0042x; 1.0042x over previous
//
#include <hip/hip_runtime.h>
#include <hip/hip_bf16.h>

#define Bd 64
#define Td 64
#define Sd 128
#define Hd 512
#define Ed 256
#define Vd 10000
#define NBLK 256

#define W0IH 0      // 6*768
#define W0HH 4608   // 6*512
#define W1IH 7680   // 6*512
#define W1HH 10752  // 6*512
#define WTOT 13824

typedef __attribute__((ext_vector_type(8))) short bf16x8;
typedef __attribute__((ext_vector_type(4))) float f32x4;

__device__ __forceinline__ float fast_tanh(float x) {
  float e = __expf(-2.0f * fabsf(x));
  float r = (1.0f - e) / (1.0f + e);
  return copysignf(r, x);
}
__device__ __forceinline__ float fast_sigmoid(float x) {
  return 1.0f / (1.0f + __expf(-x));
}
__device__ __forceinline__ float bf2f(unsigned short u) {
  return __uint_as_float(((unsigned int)u) << 16);
}
__device__ __forceinline__ void st_llc(float* p, float v) {
  __hip_atomic_store(p, v, __ATOMIC_RELAXED, __HIP_MEMORY_SCOPE_AGENT);
}
// k-quad state layout: element (k, b) lives at (k>>2)*256 + b*4 + (k&3)
__device__ __forceinline__ int q4(int k, int b) {
  return (k >> 2) * 256 + b * 4 + (k & 3);
}

// wbl2-free grid barrier (r12): relaxed arrive/go + single acquire inv.
__device__ __forceinline__ void gbar(int* arrive, int* go, int ep, int blk, int tid) {
  __syncthreads();
  if (tid == 0)
    __hip_atomic_store(&arrive[blk], ep, __ATOMIC_RELAXED, __HIP_MEMORY_SCOPE_AGENT);
  if (blk == 0) {
    if (tid < 64) {
      for (;;) {
        int a0 = __hip_atomic_load(&arrive[tid], __ATOMIC_RELAXED,
                                   __HIP_MEMORY_SCOPE_AGENT);
        int a1 = __hip_atomic_load(&arrive[tid + 64], __ATOMIC_RELAXED,
                                   __HIP_MEMORY_SCOPE_AGENT);
        int a2 = __hip_atomic_load(&arrive[tid + 128], __ATOMIC_RELAXED,
                                   __HIP_MEMORY_SCOPE_AGENT);
        int a3 = __hip_atomic_load(&arrive[tid + 192], __ATOMIC_RELAXED,
                                   __HIP_MEMORY_SCOPE_AGENT);
        if (a0 >= ep && a1 >= ep && a2 >= ep && a3 >= ep) break;
        __builtin_amdgcn_s_sleep(2);
      }
    }
    __syncthreads();
    if (tid == 0)
      __hip_atomic_store(go, ep, __ATOMIC_RELAXED, __HIP_MEMORY_SCOPE_AGENT);
  }
  if (tid == 0) {
    while (__hip_atomic_load(go, __ATOMIC_RELAXED, __HIP_MEMORY_SCOPE_AGENT) < ep) {
      __builtin_amdgcn_s_sleep(1);
    }
    __builtin_amdgcn_fence(__ATOMIC_ACQUIRE, "agent");
  }
  __syncthreads();
}

// fp32 tiled GEMM (kp prep). C[M,N] = A[M,K] @ W[N,K]^T, bf16 out.
__global__ void k_gemm_kp(const float* __restrict__ A, const float* __restrict__ W,
                          unsigned short* __restrict__ C, int M, int N, int K) {
  __shared__ __align__(16) float As[16][64];
  __shared__ __align__(16) float Ws[16][64];
  int m0 = blockIdx.x * 64, n0 = blockIdx.y * 64;
  int tid = threadIdx.x;
  int tx = tid & 15, ty = tid >> 4;
  float acc[4][4] = {};
  for (int k0 = 0; k0 < K; k0 += 16) {
#pragma unroll
    for (int i = 0; i < 4; i++) {
      int e = tid + i * 256;
      int r = e >> 4, c = e & 15;
      As[c][r] = A[(long)(m0 + r) * K + k0 + c];
      Ws[c][r] = W[(long)(n0 + r) * K + k0 + c];
    }
    __syncthreads();
#pragma unroll
    for (int k = 0; k < 16; k++) {
      float a_[4], w_[4];
#pragma unroll
      for (int i = 0; i < 4; i++) a_[i] = As[k][ty * 4 + i];
#pragma unroll
      for (int j = 0; j < 4; j++) w_[j] = Ws[k][tx * 4 + j];
#pragma unroll
      for (int i = 0; i < 4; i++)
#pragma unroll
        for (int j = 0; j < 4; j++) acc[i][j] += a_[i] * w_[j];
    }
    __syncthreads();
  }
#pragma unroll
  for (int i = 0; i < 4; i++)
#pragma unroll
    for (int j = 0; j < 4; j++) {
      __hip_bfloat16 h = __float2bfloat16(acc[i][j]);
      C[(long)(m0 + ty * 4 + i) * N + n0 + tx * 4 + j] = *(unsigned short*)&h;
    }
}

// bf16 MFMA logits GEMM
__global__ __launch_bounds__(256) void k_logits(
    const unsigned short* __restrict__ ysbf, const unsigned short* __restrict__ Wdbf,
    const float* __restrict__ bd, float* __restrict__ out, int N) {
  int m0 = blockIdx.x * 64, n0 = blockIdx.y * 64;
  int w = threadIdx.x >> 6, lane = threadIdx.x & 63;
  int row = lane & 15, kg = lane >> 4;
  int mw = m0 + w * 16;
  f32x4 acc[4] = {};
  const unsigned short* Arow = ysbf + (size_t)(mw + row) * 512 + kg * 8;
  for (int k0 = 0; k0 < 512; k0 += 32) {
    bf16x8 af = *(const bf16x8*)(Arow + k0);
#pragma unroll
    for (int nn = 0; nn < 4; nn++) {
      int ncol = n0 + nn * 16 + row;
      bf16x8 bfv = {};
      if (ncol < N) bfv = *(const bf16x8*)(Wdbf + (size_t)ncol * 512 + k0 + kg * 8);
      acc[nn] = __builtin_amdgcn_mfma_f32_16x16x32_bf16(af, bfv, acc[nn], 0, 0, 0);
    }
  }
#pragma unroll
  for (int nn = 0; nn < 4; nn++) {
    int ncol = n0 + nn * 16 + row;
    if (ncol < N) {
      float bv = bd[ncol];
#pragma unroll
      for (int r = 0; r < 4; r++) {
        int mm = mw + kg * 4 + r;
        int t_ = mm >> 6, b_ = mm & 63;
        out[((size_t)(b_ * Td + t_)) * N + ncol] = acc[nn][r] + bv;
      }
    }
  }
}

// elementwise f32 -> bf16 copy
__global__ void k_tobf(const float* __restrict__ src, unsigned short* __restrict__ dst,
                       long n) {
  long i = (long)blockIdx.x * 1024 + threadIdx.x;
  if (i < n) {
    __hip_bfloat16 h = __float2bfloat16(src[i]);
    dst[i] = *(unsigned short*)&h;
  }
}

// WqT[k][n] = bf16(Wq[n][k]) — tiled transpose
__global__ void k_wqT(const float* __restrict__ Wq, unsigned short* __restrict__ WqT) {
  __shared__ float tile[64][65];
  int bi = blockIdx.x, bj = blockIdx.y;
  int tx = threadIdx.x & 63, ty = threadIdx.x >> 6;  // 256 threads
  for (int i = 0; i < 64; i += 4)
    tile[ty + i][tx] = Wq[(size_t)(bi * 64 + ty + i) * 512 + bj * 64 + tx];
  __syncthreads();
  for (int i = 0; i < 64; i += 4) {
    int r = ty + i;
    __hip_bfloat16 h = __float2bfloat16(tile[tx][r]);
    WqT[(size_t)(bj * 64 + r) * 512 + bi * 64 + tx] = *(unsigned short*)&h;
  }
}

// embTf: k-quad layout per t
__global__ void k_embT(const int* __restrict__ x, const float* __restrict__ emb,
                       float* __restrict__ embTf) {
  __shared__ int rows[64];
  int t = blockIdx.x;
  if (threadIdx.x < 64) rows[threadIdx.x] = x[threadIdx.x * Td + t];
  __syncthreads();
  int e = threadIdx.x;
  for (int b = 0; b < 64; b++) {
    embTf[(size_t)t * 16384 + q4(e, b)] = emb[(long)rows[b] * Ed + e];
  }
}

// GRU cell phase (r15 verbatim): waves 0-3 ih k-quarters (6 rows each), 4-7 hh
// k-quarters, 8-11 (C0) emb e-quarters. State float4 loads; weights LDS
// broadcast. Combine (4 partials) + nonlinearity by threads 0-127.
template <bool C0>
__device__ __forceinline__ void cell_phase(
    int blk, int tid, int t, const float* __restrict__ aT,
    const float* __restrict__ embTf, const float* __restrict__ hT,
    const float* wIH, const float* wHH, const float* __restrict__ bih,
    const float* __restrict__ bhh, const float* __restrict__ den,
    float* __restrict__ houtT, unsigned short* __restrict__ ysbf, float* scratch) {
  int lane = tid & 63;
  int w = tid >> 6;
  const int RIH = C0 ? 768 : 512;
  float* ps = scratch;          // [12 rows][4 quarters][64]
  float* psE = scratch + 3072;  // [6][4][64]
  if (w < 8) {
    int strm = w >> 2, qk = w & 3;
    const float* A = (strm == 0 ? aT : hT) + qk * 32 * 256;
    float a[6] = {0.f, 0.f, 0.f, 0.f, 0.f, 0.f};
#pragma unroll 8
    for (int k4 = 0; k4 < 32; k4++) {
      float4 av = *(const float4*)&A[k4 * 256 + lane * 4];
#pragma unroll
      for (int r = 0; r < 6; r++) {
        const float* wr = (strm == 0 ? wIH + (size_t)r * RIH : wHH + (size_t)r * 512) +
                          qk * 128 + k4 * 4;
        float4 w4 = *(const float4*)wr;
        a[r] += av.x * w4.x + av.y * w4.y + av.z * w4.z + av.w * w4.w;
      }
    }
    if (C0 && strm == 0) {
      float inv = 1.0f / den[lane];
#pragma unroll
      for (int r = 0; r < 6; r++) a[r] *= inv;
    }
    int base = strm * 6;
#pragma unroll
    for (int r = 0; r < 6; r++) ps[((base + r) * 4 + qk) * 64 + lane] = a[r];
  } else if (C0 && w < 12) {
    int qe = w - 8;
    const float* ef = embTf + (size_t)t * 16384 + qe * 16 * 256;
    float a[6] = {0.f, 0.f, 0.f, 0.f, 0.f, 0.f};
#pragma unroll 8
    for (int k4 = 0; k4 < 16; k4++) {
      float4 ev = *(const float4*)&ef[k4 * 256 + lane * 4];
#pragma unroll
      for (int r = 0; r < 6; r++) {
        const float* wr = wIH + (size_t)r * 768 + 512 + qe * 64 + k4 * 4;
        float4 w4 = *(const float4*)wr;
        a[r] += ev.x * w4.x + ev.y * w4.y + ev.z * w4.z + ev.w * w4.w;
      }
    }
#pragma unroll
    for (int r = 0; r < 6; r++) psE[(r * 4 + qe) * 64 + lane] = a[r];
  }
  __syncthreads();
  if (tid < 128) {
    int jl = tid >> 6, b = tid & 63;
#define RD(R)                                                              \
  (ps[((R)*4 + 0) * 64 + b] + ps[((R)*4 + 1) * 64 + b] +                   \
   ps[((R)*4 + 2) * 64 + b] + ps[((R)*4 + 3) * 64 + b])
#define RE(R)                                                              \
  (psE[((R)*4 + 0) * 64 + b] + psE[((R)*4 + 1) * 64 + b] +                 \
   psE[((R)*4 + 2) * 64 + b] + psE[((R)*4 + 3) * 64 + b])
    float ir = RD(0 + jl);
    float iz = RD(2 + jl);
    float in = RD(4 + jl);
    if (C0) {
      ir += RE(0 + jl);
      iz += RE(2 + jl);
      in += RE(4 + jl);
    }
    float hr = RD(6 + jl);
    float hz = RD(8 + jl);
    float hn_ = RD(10 + jl);
#undef RD
#undef RE
    int j = blk * 2 + jl;
    float r = fast_sigmoid(ir + hr + bih[j] + bhh[j]);
    float z = fast_sigmoid(iz + hz + bih[Hd + j] + bhh[Hd + j]);
    float n = fast_tanh(in + bih[2 * Hd + j] + r * (hn_ + bhh[2 * Hd + j]));
    float hp = hT[q4(j, b)];
    float out = (1.f - z) * n + z * hp;
    st_llc(&houtT[q4(j, b)], out);
    if (!C0) {
      __hip_bfloat16 hb = __float2bfloat16(out);
      ysbf[((size_t)t * 64 + b) * 512 + j] = *(unsigned short*)&hb;
    }
  }
}

__global__ __launch_bounds__(1024, 1) void k_decoder(
    const float* __restrict__ h0_in, const int* __restrict__ vlen,
    const unsigned short* __restrict__ WqTbf, const float* __restrict__ wvp,
    const float* __restrict__ Wih0, const float* __restrict__ Whh0,
    const float* __restrict__ bih0, const float* __restrict__ bhh0,
    const float* __restrict__ Wih1, const float* __restrict__ Whh1,
    const float* __restrict__ bih1, const float* __restrict__ bhh1,
    const unsigned short* __restrict__ kpbf, const unsigned short* __restrict__ encbf,
    const float* __restrict__ embTf, int* bar, float* ctxT, float* den,
    float* h0TA, float* h0TB, float* h1TA, float* h1TB, unsigned short* ysbf) {
  __shared__ __align__(16) float wLDS[WTOT];               // 55296 B
  __shared__ __align__(16) unsigned short kpL[32 * 512];   // 32768 B
  __shared__ __align__(16) unsigned short encL[32 * 512];  // 32768 B
  __shared__ __align__(16) float scratch[8704];            // 34816 B (union)
  __shared__ __align__(16) float h1s[512];                 // 2048 B
  __shared__ float scS[40];
  int blk = blockIdx.x, tid = threadIdx.x;
  int lane = tid & 63;
  int w = tid >> 6;
  int battn = blk >> 2, q = blk & 3;
  int* arrive = bar;
  int* go = bar + NBLK;
  int ep = 0;

  // ---- one-time staging ----
  {
    int j0 = blk * 2;
#pragma unroll
    for (int rr = 0; rr < 6; rr++) {
      int g = rr >> 1, jl = rr & 1;
      int row = g * Hd + j0 + jl;
      const float* s0 = Wih0 + (size_t)row * 768;
      for (int k = tid; k < 768; k += 1024) wLDS[W0IH + rr * 768 + k] = s0[k];
      const float* s1 = Whh0 + (size_t)row * Hd;
      for (int k = tid; k < Hd; k += 1024) wLDS[W0HH + rr * 512 + k] = s1[k];
      const float* s2 = Wih1 + (size_t)row * Hd;
      for (int k = tid; k < Hd; k += 1024) wLDS[W1IH + rr * 512 + k] = s2[k];
      const float* s3 = Whh1 + (size_t)row * Hd;
      for (int k = tid; k < Hd; k += 1024) wLDS[W1HH + rr * 512 + k] = s3[k];
    }
    const uint4* ksrc = (const uint4*)(kpbf + ((size_t)battn * Sd + q * 32) * Hd);
    const uint4* esrc = (const uint4*)(encbf + ((size_t)battn * Sd + q * 32) * Hd);
    uint4* kdst = (uint4*)kpL;
    uint4* edst = (uint4*)encL;
    for (int i = tid; i < 2048; i += 1024) {
      kdst[i] = ksrc[i];
      edst[i] = esrc[i];
    }
  }
  float wvr[8];
#pragma unroll
  for (int i = 0; i < 8; i++) wvr[i] = wvp[lane * 8 + i];

  // init: h0 transpose into k-quad buffers; zero ctxT/den
  if (blk < Bd) {
    int b = blk;
    for (int k = tid; k < Hd; k += 1024) {
      st_llc(&h0TA[q4(k, b)], h0_in[(0 * Bd + b) * Hd + k]);
      st_llc(&h1TA[q4(k, b)], h0_in[(1 * Bd + b) * Hd + k]);
    }
  }
  if (tid < 128) st_llc(&ctxT[blk * 128 + tid], 0.f);
  if (blk < Bd && tid == 128) st_llc(&den[blk], 0.f);
  gbar(arrive, go, ++ep, blk, tid);

  for (int t = 0; t < Td; t++) {
    const float* h0prev = (t & 1) ? h0TB : h0TA;
    float* h0next = (t & 1) ? h0TA : h0TB;
    const float* h1prev = (t & 1) ? h1TB : h1TA;
    float* h1next = (t & 1) ? h1TA : h1TB;

    // ---- P1: FUSED qproj + attention partial (b=battn) ----
    {
      int b = battn;
      // stage h1[b,:] into LDS (read once per block)
      if (tid < 512) h1s[tid] = h1prev[q4(tid, b)];
      __syncthreads();
      float* qpP = scratch;         // [16][512] partials (float4 stores)
      float* qpF = scratch + 8192;  // [512]
      {
        float p0 = 0.f, p1 = 0.f, p2 = 0.f, p3 = 0.f;
        float p4 = 0.f, p5 = 0.f, p6 = 0.f, p7 = 0.f;
        const unsigned short* Wt = WqTbf + (size_t)(w * 32) * 512 + lane * 8;
#pragma unroll 8
        for (int kk = 0; kk < 32; kk++) {
          float hv = h1s[w * 32 + kk];
          uint4 u = *(const uint4*)(Wt + (size_t)kk * 512);
          p0 += hv * __uint_as_float(u.x << 16);
          p1 += hv * __uint_as_float(u.x & 0xffff0000u);
          p2 += hv * __uint_as_float(u.y << 16);
          p3 += hv * __uint_as_float(u.y & 0xffff0000u);
          p4 += hv * __uint_as_float(u.z << 16);
          p5 += hv * __uint_as_float(u.z & 0xffff0000u);
          p6 += hv * __uint_as_float(u.w << 16);
          p7 += hv * __uint_as_float(u.w & 0xffff0000u);
        }
        float4 v0 = {p0, p1, p2, p3};
        float4 v1 = {p4, p5, p6, p7};
        *(float4*)&qpP[w * 512 + lane * 8] = v0;
        *(float4*)&qpP[w * 512 + lane * 8 + 4] = v1;
      }
      __syncthreads();
      if (tid < 512) {
        float s = 0.f;
#pragma unroll
        for (int ww = 0; ww < 16; ww++) s += qpP[ww * 512 + tid];
        qpF[tid] = s;
      }
      __syncthreads();
      float qv[8];
#pragma unroll
      for (int i = 0; i < 8; i++) qv[i] = qpF[lane * 8 + i];
      int vl = vlen[b];
      // scores: wave w -> s_local = 2w, 2w+1 (32 s-rows in LDS)
#pragma unroll
      for (int si = 0; si < 2; si++) {
        int sl = w * 2 + si;
        uint4 kw = *(const uint4*)&kpL[sl * 512 + lane * 8];
        float f0 = __uint_as_float(kw.x << 16);
        float f1 = __uint_as_float(kw.x & 0xffff0000u);
        float f2 = __uint_as_float(kw.y << 16);
        float f3 = __uint_as_float(kw.y & 0xffff0000u);
        float f4 = __uint_as_float(kw.z << 16);
        float f5 = __uint_as_float(kw.z & 0xffff0000u);
        float f6 = __uint_as_float(kw.w << 16);
        float f7 = __uint_as_float(kw.w & 0xffff0000u);
        float acc = wvr[0] * fast_tanh(qv[0] + f0) + wvr[1] * fast_tanh(qv[1] + f1) +
                    wvr[2] * fast_tanh(qv[2] + f2) + wvr[3] * fast_tanh(qv[3] + f3) +
                    wvr[4] * fast_tanh(qv[4] + f4) + wvr[5] * fast_tanh(qv[5] + f5) +
                    wvr[6] * fast_tanh(qv[6] + f6) + wvr[7] * fast_tanh(qv[7] + f7);
#pragma unroll
        for (int off = 1; off < 64; off <<= 1) acc += __shfl_xor(acc, off);
        if (lane == 0) {
          int s = q * 32 + sl;
          scS[sl] = (s < vl) ? __expf(acc) : 0.f;  // no-max softmax: |score|<=~9
        }
      }
      __syncthreads();
      if (tid < 32) {
        float p2 = scS[tid];
#pragma unroll
        for (int off = 1; off < 32; off <<= 1) p2 += __shfl_xor(p2, off, 32);
        if (tid == 0) atomicAdd(&den[b], p2);
      }
      if (tid < 512) {
        float acc = 0.f;
#pragma unroll 8
        for (int s = 0; s < 32; s++) acc += scS[s] * bf2f(encL[s * 512 + tid]);
        atomicAdd(&ctxT[q4(tid, b)], acc);
      }
    }
    gbar(arrive, go, ++ep, blk, tid);

    // ---- P2: GRU cell 0 ----
    cell_phase<true>(blk, tid, t, ctxT, embTf, h0prev, wLDS + W0IH, wLDS + W0HH,
                     bih0, bhh0, den, h0next, nullptr, scratch);
    gbar(arrive, go, ++ep, blk, tid);

    // ---- P3: zero ctxT/den + GRU cell 1 ----
    if (tid < 128) st_llc(&ctxT[blk * 128 + tid], 0.f);
    if (blk < Bd && tid == 128) st_llc(&den[blk], 0.f);
    cell_phase<false>(blk, tid, t, h0next, nullptr, h1prev, wLDS + W1IH,
                      wLDS + W1HH, bih1, bhh1, nullptr, h1next, ysbf, scratch);
    gbar(arrive, go, ++ep, blk, tid);
  }
}

extern "C" void kernel_launch(void* const* d_in, const int* in_sizes, int n_in,
                              void* d_out, int out_size, void* d_ws, size_t ws_size,
                              hipStream_t stream) {
  const int* x = (const int*)d_in[0];
  const float* enc = (const float*)d_in[1];
  const float* h0 = (const float*)d_in[2];
  const int* vlen = (const int*)d_in[3];
  const float* emb = (const float*)d_in[4];
  const float* Wq = (const float*)d_in[5];
  const float* Wk = (const float*)d_in[6];
  const float* wv = (const float*)d_in[7];
  const float* W_ih0 = (const float*)d_in[8];
  const float* W_hh0 = (const float*)d_in[9];
  const float* b_ih0 = (const float*)d_in[10];
  const float* b_hh0 = (const float*)d_in[11];
  const float* W_ih1 = (const float*)d_in[12];
  const float* W_hh1 = (const float*)d_in[13];
  const float* b_ih1 = (const float*)d_in[14];
  const float* b_hh1 = (const float*)d_in[15];
  const float* Wd = (const float*)d_in[16];
  const float* bd = (const float*)d_in[17];
  float* out = (float*)d_out;

  char* p = (char*)d_ws;
  int* bar = (int*)p;
  p += 2048;
  unsigned short* kpbf = (unsigned short*)p;   // B*S*H bf16
  p += (size_t)Bd * Sd * Hd * 2;
  unsigned short* encbf = (unsigned short*)p;  // B*S*H bf16
  p += (size_t)Bd * Sd * Hd * 2;
  unsigned short* Wdbf = (unsigned short*)p;   // V*H bf16
  p += (size_t)Vd * Hd * 2;
  unsigned short* WqTbf = (unsigned short*)p;  // H*H bf16 (transposed)
  p += (size_t)Hd * Hd * 2;
  unsigned short* ysbf = (unsigned short*)p;   // T*B*H bf16
  p += (size_t)Td * Bd * Hd * 2;
  float* embTf = (float*)p;  // T*E*B f32 (k-quad)
  p += (size_t)Td * Ed * Bd * 4;
  float* ctxT = (float*)p;  p += (size_t)Hd * Bd * 4;
  float* den = (float*)p;   p += 256;
  float* h0TA = (float*)p;  p += (size_t)Hd * Bd * 4;
  float* h0TB = (float*)p;  p += (size_t)Hd * Bd * 4;
  float* h1TA = (float*)p;  p += (size_t)Hd * Bd * 4;
  float* h1TB = (float*)p;

  hipMemsetAsync(bar, 0, 2048, stream);

  // kp = enc @ Wk^T -> bf16
  k_gemm_kp<<<dim3(128, 8), 256, 0, stream>>>(enc, Wk, kpbf, Bd * Sd, Hd, Hd);
  // enc, Wd -> bf16; Wq -> bf16 transposed
  long nenc = (long)Bd * Sd * Hd;
  k_tobf<<<(nenc + 1023) / 1024, 1024, 0, stream>>>(enc, encbf, nenc);
  long nwd = (long)Vd * Hd;
  k_tobf<<<(nwd + 1023) / 1024, 1024, 0, stream>>>(Wd, Wdbf, nwd);
  k_wqT<<<dim3(8, 8), 256, 0, stream>>>(Wq, WqTbf);
  // embTf gather+transpose (f32, k-quad)
  k_embT<<<Td, 256, 0, stream>>>(x, emb, embTf);
  // fused 64-step decoder (3 barriers/step)
  k_decoder<<<NBLK, 1024, 0, stream>>>(h0, vlen, WqTbf, wv, W_ih0, W_hh0, b_ih0,
                                       b_hh0, W_ih1, W_hh1, b_ih1, b_hh1, kpbf,
                                       encbf, embTf, bar, ctxT, den, h0TA, h0TB,
                                       h1TA, h1TB, ysbf);
  // logits: bf16 MFMA GEMM
  k_logits<<<dim3(64, 157), 256, 0, stream>>>(ysbf, Wdbf, bd, out, Vd);
}

// Round 18
// 3654.692 us; speedup vs baseline: 1.0710x; 1.0666x over previous
//
#include <hip/hip_runtime.h>
#include <hip/hip_bf16.h>

#define Bd 64
#define Td 64
#define Sd 128
#define Hd 512
#define Ed 256
#define Vd 10000
#define NBLK 256

#define W0IH 0      // 6*768
#define W0HH 4608   // 6*512
#define W1IH 7680   // 6*512
#define W1HH 10752  // 6*512
#define WTOT 13824

typedef __attribute__((ext_vector_type(8))) short bf16x8;
typedef __attribute__((ext_vector_type(4))) float f32x4;

__device__ __forceinline__ float fast_tanh(float x) {
  float e = __expf(-2.0f * fabsf(x));
  float r = (1.0f - e) / (1.0f + e);
  return copysignf(r, x);
}
__device__ __forceinline__ float fast_sigmoid(float x) {
  return 1.0f / (1.0f + __expf(-x));
}
__device__ __forceinline__ float bf2f(unsigned short u) {
  return __uint_as_float(((unsigned int)u) << 16);
}
__device__ __forceinline__ void st_llc(float* p, float v) {
  __hip_atomic_store(p, v, __ATOMIC_RELAXED, __HIP_MEMORY_SCOPE_AGENT);
}
// k-quad state layout: element (k, b) lives at (k>>2)*256 + b*4 + (k&3)
__device__ __forceinline__ int q4(int k, int b) {
  return (k >> 2) * 256 + b * 4 + (k & 3);
}

// wbl2-free grid barrier (r12): relaxed arrive/go + single acquire inv.
__device__ __forceinline__ void gbar(int* arrive, int* go, int ep, int blk, int tid) {
  __syncthreads();
  if (tid == 0)
    __hip_atomic_store(&arrive[blk], ep, __ATOMIC_RELAXED, __HIP_MEMORY_SCOPE_AGENT);
  if (blk == 0) {
    if (tid < 64) {
      for (;;) {
        int a0 = __hip_atomic_load(&arrive[tid], __ATOMIC_RELAXED,
                                   __HIP_MEMORY_SCOPE_AGENT);
        int a1 = __hip_atomic_load(&arrive[tid + 64], __ATOMIC_RELAXED,
                                   __HIP_MEMORY_SCOPE_AGENT);
        int a2 = __hip_atomic_load(&arrive[tid + 128], __ATOMIC_RELAXED,
                                   __HIP_MEMORY_SCOPE_AGENT);
        int a3 = __hip_atomic_load(&arrive[tid + 192], __ATOMIC_RELAXED,
                                   __HIP_MEMORY_SCOPE_AGENT);
        if (a0 >= ep && a1 >= ep && a2 >= ep && a3 >= ep) break;
        __builtin_amdgcn_s_sleep(2);
      }
    }
    __syncthreads();
    if (tid == 0)
      __hip_atomic_store(go, ep, __ATOMIC_RELAXED, __HIP_MEMORY_SCOPE_AGENT);
  }
  if (tid == 0) {
    while (__hip_atomic_load(go, __ATOMIC_RELAXED, __HIP_MEMORY_SCOPE_AGENT) < ep) {
      __builtin_amdgcn_s_sleep(1);
    }
    __builtin_amdgcn_fence(__ATOMIC_ACQUIRE, "agent");
  }
  __syncthreads();
}

// fp32 tiled GEMM (kp prep). C[M,N] = A[M,K] @ W[N,K]^T, bf16 out.
__global__ void k_gemm_kp(const float* __restrict__ A, const float* __restrict__ W,
                          unsigned short* __restrict__ C, int M, int N, int K) {
  __shared__ __align__(16) float As[16][64];
  __shared__ __align__(16) float Ws[16][64];
  int m0 = blockIdx.x * 64, n0 = blockIdx.y * 64;
  int tid = threadIdx.x;
  int tx = tid & 15, ty = tid >> 4;
  float acc[4][4] = {};
  for (int k0 = 0; k0 < K; k0 += 16) {
#pragma unroll
    for (int i = 0; i < 4; i++) {
      int e = tid + i * 256;
      int r = e >> 4, c = e & 15;
      As[c][r] = A[(long)(m0 + r) * K + k0 + c];
      Ws[c][r] = W[(long)(n0 + r) * K + k0 + c];
    }
    __syncthreads();
#pragma unroll
    for (int k = 0; k < 16; k++) {
      float a_[4], w_[4];
#pragma unroll
      for (int i = 0; i < 4; i++) a_[i] = As[k][ty * 4 + i];
#pragma unroll
      for (int j = 0; j < 4; j++) w_[j] = Ws[k][tx * 4 + j];
#pragma unroll
      for (int i = 0; i < 4; i++)
#pragma unroll
        for (int j = 0; j < 4; j++) acc[i][j] += a_[i] * w_[j];
    }
    __syncthreads();
  }
#pragma unroll
  for (int i = 0; i < 4; i++)
#pragma unroll
    for (int j = 0; j < 4; j++) {
      __hip_bfloat16 h = __float2bfloat16(acc[i][j]);
      C[(long)(m0 + ty * 4 + i) * N + n0 + tx * 4 + j] = *(unsigned short*)&h;
    }
}

// bf16 MFMA logits GEMM
__global__ __launch_bounds__(256) void k_logits(
    const unsigned short* __restrict__ ysbf, const unsigned short* __restrict__ Wdbf,
    const float* __restrict__ bd, float* __restrict__ out, int N) {
  int m0 = blockIdx.x * 64, n0 = blockIdx.y * 64;
  int w = threadIdx.x >> 6, lane = threadIdx.x & 63;
  int row = lane & 15, kg = lane >> 4;
  int mw = m0 + w * 16;
  f32x4 acc[4] = {};
  const unsigned short* Arow = ysbf + (size_t)(mw + row) * 512 + kg * 8;
  for (int k0 = 0; k0 < 512; k0 += 32) {
    bf16x8 af = *(const bf16x8*)(Arow + k0);
#pragma unroll
    for (int nn = 0; nn < 4; nn++) {
      int ncol = n0 + nn * 16 + row;
      bf16x8 bfv = {};
      if (ncol < N) bfv = *(const bf16x8*)(Wdbf + (size_t)ncol * 512 + k0 + kg * 8);
      acc[nn] = __builtin_amdgcn_mfma_f32_16x16x32_bf16(af, bfv, acc[nn], 0, 0, 0);
    }
  }
#pragma unroll
  for (int nn = 0; nn < 4; nn++) {
    int ncol = n0 + nn * 16 + row;
    if (ncol < N) {
      float bv = bd[ncol];
#pragma unroll
      for (int r = 0; r < 4; r++) {
        int mm = mw + kg * 4 + r;
        int t_ = mm >> 6, b_ = mm & 63;
        out[((size_t)(b_ * Td + t_)) * N + ncol] = acc[nn][r] + bv;
      }
    }
  }
}

// elementwise f32 -> bf16 copy
__global__ void k_tobf(const float* __restrict__ src, unsigned short* __restrict__ dst,
                       long n) {
  long i = (long)blockIdx.x * 1024 + threadIdx.x;
  if (i < n) {
    __hip_bfloat16 h = __float2bfloat16(src[i]);
    dst[i] = *(unsigned short*)&h;
  }
}

// embTf: k-quad layout per t
__global__ void k_embT(const int* __restrict__ x, const float* __restrict__ emb,
                       float* __restrict__ embTf) {
  __shared__ int rows[64];
  int t = blockIdx.x;
  if (threadIdx.x < 64) rows[threadIdx.x] = x[threadIdx.x * Td + t];
  __syncthreads();
  int e = threadIdx.x;
  for (int b = 0; b < 64; b++) {
    embTf[(size_t)t * 16384 + q4(e, b)] = emb[(long)rows[b] * Ed + e];
  }
}

// GRU cell phase, READ-ONCE: waves 0-3 ih k-quarters (6 rows each), 4-7 hh
// k-quarters, 8-11 (C0) emb e-quarters. State float4 loads; weights LDS
// broadcast. Combine (4 partials) + nonlinearity by threads 0-127.
template <bool C0>
__device__ __forceinline__ void cell_phase(
    int blk, int tid, int t, const float* __restrict__ aT,
    const float* __restrict__ embTf, const float* __restrict__ hT,
    const float* wIH, const float* wHH, const float* __restrict__ bih,
    const float* __restrict__ bhh, const float* __restrict__ den,
    float* __restrict__ houtT, unsigned short* __restrict__ ysbf, float* scratch) {
  int lane = tid & 63;
  int w = tid >> 6;
  const int RIH = C0 ? 768 : 512;
  float* ps = scratch;          // [12 rows][4 quarters][64]
  float* psE = scratch + 3072;  // [6][4][64]
  if (w < 8) {
    int strm = w >> 2, qk = w & 3;
    const float* A = (strm == 0 ? aT : hT) + qk * 32 * 256;
    float a[6] = {0.f, 0.f, 0.f, 0.f, 0.f, 0.f};
#pragma unroll 8
    for (int k4 = 0; k4 < 32; k4++) {
      float4 av = *(const float4*)&A[k4 * 256 + lane * 4];
#pragma unroll
      for (int r = 0; r < 6; r++) {
        const float* wr = (strm == 0 ? wIH + (size_t)r * RIH : wHH + (size_t)r * 512) +
                          qk * 128 + k4 * 4;
        float4 w4 = *(const float4*)wr;
        a[r] += av.x * w4.x + av.y * w4.y + av.z * w4.z + av.w * w4.w;
      }
    }
    if (C0 && strm == 0) {
      float inv = 1.0f / den[lane];
#pragma unroll
      for (int r = 0; r < 6; r++) a[r] *= inv;
    }
    int base = strm * 6;
#pragma unroll
    for (int r = 0; r < 6; r++) ps[((base + r) * 4 + qk) * 64 + lane] = a[r];
  } else if (C0 && w < 12) {
    int qe = w - 8;
    const float* ef = embTf + (size_t)t * 16384 + qe * 16 * 256;
    float a[6] = {0.f, 0.f, 0.f, 0.f, 0.f, 0.f};
#pragma unroll 8
    for (int k4 = 0; k4 < 16; k4++) {
      float4 ev = *(const float4*)&ef[k4 * 256 + lane * 4];
#pragma unroll
      for (int r = 0; r < 6; r++) {
        const float* wr = wIH + (size_t)r * 768 + 512 + qe * 64 + k4 * 4;
        float4 w4 = *(const float4*)wr;
        a[r] += ev.x * w4.x + ev.y * w4.y + ev.z * w4.z + ev.w * w4.w;
      }
    }
#pragma unroll
    for (int r = 0; r < 6; r++) psE[(r * 4 + qe) * 64 + lane] = a[r];
  }
  __syncthreads();
  if (tid < 128) {
    int jl = tid >> 6, b = tid & 63;
    float invd = C0 ? (1.0f / den[b]) : 1.0f;
#define RD(R)                                                              \
  (ps[((R)*4 + 0) * 64 + b] + ps[((R)*4 + 1) * 64 + b] +                   \
   ps[((R)*4 + 2) * 64 + b] + ps[((R)*4 + 3) * 64 + b])
#define RE(R)                                                              \
  (psE[((R)*4 + 0) * 64 + b] + psE[((R)*4 + 1) * 64 + b] +                 \
   psE[((R)*4 + 2) * 64 + b] + psE[((R)*4 + 3) * 64 + b])
    float ir = RD(0 + jl);
    float iz = RD(2 + jl);
    float in = RD(4 + jl);
    if (C0) {
      ir += RE(0 + jl);
      iz += RE(2 + jl);
      in += RE(4 + jl);
    }
    float hr = RD(6 + jl);
    float hz = RD(8 + jl);
    float hn_ = RD(10 + jl);
#undef RD
#undef RE
    int j = blk * 2 + jl;
    float r = fast_sigmoid(ir + hr + bih[j] + bhh[j]);
    float z = fast_sigmoid(iz + hz + bih[Hd + j] + bhh[Hd + j]);
    float n = fast_tanh(in + bih[2 * Hd + j] + r * (hn_ + bhh[2 * Hd + j]));
    float hp = hT[q4(j, b)];
    float out = (1.f - z) * n + z * hp;
    st_llc(&houtT[q4(j, b)], out);
    if (!C0) {
      __hip_bfloat16 hb = __float2bfloat16(out);
      ysbf[((size_t)t * 64 + b) * 512 + j] = *(unsigned short*)&hb;
    }
  }
}

__global__ __launch_bounds__(1024, 1) void k_decoder(
    const float* __restrict__ h0_in, const int* __restrict__ vlen,
    const float* __restrict__ Wq, const float* __restrict__ wvp,
    const float* __restrict__ Wih0, const float* __restrict__ Whh0,
    const float* __restrict__ bih0, const float* __restrict__ bhh0,
    const float* __restrict__ Wih1, const float* __restrict__ Whh1,
    const float* __restrict__ bih1, const float* __restrict__ bhh1,
    const unsigned short* __restrict__ kpbf, const unsigned short* __restrict__ encbf,
    const float* __restrict__ embTf, int* bar, float* qpN, float* ctxT,
    float* den, float* h0TA, float* h0TB, float* h1TA, float* h1TB,
    unsigned short* ysbf) {
  __shared__ __align__(16) float wLDS[WTOT];               // 55296 B
  __shared__ __align__(16) float WqL[1024];                // 4096 B
  __shared__ __align__(16) unsigned short kpL[32 * 512];   // 32768 B
  __shared__ __align__(16) unsigned short encL[32 * 512];  // 32768 B
  __shared__ __align__(16) float scratch[4608];            // 18432 B (union)
  int blk = blockIdx.x, tid = threadIdx.x;
  int lane = tid & 63;
  int w = tid >> 6;
  int battn = blk >> 2, q = blk & 3;
  int* arrive = bar;
  int* go = bar + NBLK;
  int ep = 0;

  // ---- one-time staging ----
  {
    int j0 = blk * 2;
#pragma unroll
    for (int rr = 0; rr < 6; rr++) {
      int g = rr >> 1, jl = rr & 1;
      int row = g * Hd + j0 + jl;
      const float* s0 = Wih0 + (size_t)row * 768;
      for (int k = tid; k < 768; k += 1024) wLDS[W0IH + rr * 768 + k] = s0[k];
      const float* s1 = Whh0 + (size_t)row * Hd;
      for (int k = tid; k < Hd; k += 1024) wLDS[W0HH + rr * 512 + k] = s1[k];
      const float* s2 = Wih1 + (size_t)row * Hd;
      for (int k = tid; k < Hd; k += 1024) wLDS[W1IH + rr * 512 + k] = s2[k];
      const float* s3 = Whh1 + (size_t)row * Hd;
      for (int k = tid; k < Hd; k += 1024) wLDS[W1HH + rr * 512 + k] = s3[k];
    }
    WqL[tid] = Wq[(size_t)(blk * 2 + (tid >> 9)) * Hd + (tid & 511)];
    const uint4* ksrc = (const uint4*)(kpbf + ((size_t)battn * Sd + q * 32) * Hd);
    const uint4* esrc = (const uint4*)(encbf + ((size_t)battn * Sd + q * 32) * Hd);
    uint4* kdst = (uint4*)kpL;
    uint4* edst = (uint4*)encL;
    for (int i = tid; i < 2048; i += 1024) {
      kdst[i] = ksrc[i];
      edst[i] = esrc[i];
    }
  }
  float wvr[8];
#pragma unroll
  for (int i = 0; i < 8; i++) wvr[i] = wvp[lane * 8 + i];

  // init: h0 transpose into k-quad buffers; zero ctxT/den
  if (blk < Bd) {
    int b = blk;
    for (int k = tid; k < Hd; k += 1024) {
      st_llc(&h0TA[q4(k, b)], h0_in[(0 * Bd + b) * Hd + k]);
      st_llc(&h1TA[q4(k, b)], h0_in[(1 * Bd + b) * Hd + k]);
    }
  }
  if (tid < 128) st_llc(&ctxT[blk * 128 + tid], 0.f);
  if (blk < Bd && tid == 128) st_llc(&den[blk], 0.f);
  gbar(arrive, go, ++ep, blk, tid);

  for (int t = 0; t < Td; t++) {
    const float* h0prev = (t & 1) ? h0TB : h0TA;
    float* h0next = (t & 1) ? h0TA : h0TB;
    const float* h1prev = (t & 1) ? h1TB : h1TA;
    float* h1next = (t & 1) ? h1TA : h1TB;

    // ---- P0: qproj, 256 blocks x 2 rows; h1 read as k-quad float4 ----
    {
      int rl = w >> 3, ks = w & 7;
      const float* qrow = &WqL[rl * 512 + ks * 64];
      const float* hp4 = h1prev + (ks * 16) * 256 + lane * 4;
      float acc = 0.f;
#pragma unroll
      for (int kk = 0; kk < 64; kk += 4) {
        float4 hv = *(const float4*)&hp4[(kk >> 2) * 256];
        acc += hv.x * qrow[kk] + hv.y * qrow[kk + 1] + hv.z * qrow[kk + 2] +
               hv.w * qrow[kk + 3];
      }
      scratch[w * 64 + lane] = acc;
      __syncthreads();
      if (tid < 128) {
        int rl2 = tid >> 6, b = tid & 63;
        float s = 0.f;
#pragma unroll
        for (int qq = 0; qq < 8; qq++) s += scratch[(rl2 * 8 + qq) * 64 + b];
        st_llc(&qpN[(size_t)b * 512 + blk * 2 + rl2], s);
      }
    }
    gbar(arrive, go, ++ep, blk, tid);

    // ---- P1: attention partial (b=battn, 32 s-rows from LDS) ----
    {
      int b = battn;
      float* sc = scratch;  // [32]
      float qv[8];
      const float* qb = qpN + (size_t)b * 512 + lane * 8;
#pragma unroll
      for (int i = 0; i < 8; i++) qv[i] = qb[i];
      int vl = vlen[b];
#pragma unroll
      for (int si = 0; si < 2; si++) {
        int sl = w * 2 + si;
        uint4 kw = *(const uint4*)&kpL[sl * 512 + lane * 8];
        float f0 = __uint_as_float(kw.x << 16);
        float f1 = __uint_as_float(kw.x & 0xffff0000u);
        float f2 = __uint_as_float(kw.y << 16);
        float f3 = __uint_as_float(kw.y & 0xffff0000u);
        float f4 = __uint_as_float(kw.z << 16);
        float f5 = __uint_as_float(kw.z & 0xffff0000u);
        float f6 = __uint_as_float(kw.w << 16);
        float f7 = __uint_as_float(kw.w & 0xffff0000u);
        float acc = wvr[0] * fast_tanh(qv[0] + f0) + wvr[1] * fast_tanh(qv[1] + f1) +
                    wvr[2] * fast_tanh(qv[2] + f2) + wvr[3] * fast_tanh(qv[3] + f3) +
                    wvr[4] * fast_tanh(qv[4] + f4) + wvr[5] * fast_tanh(qv[5] + f5) +
                    wvr[6] * fast_tanh(qv[6] + f6) + wvr[7] * fast_tanh(qv[7] + f7);
#pragma unroll
        for (int off = 1; off < 64; off <<= 1) acc += __shfl_xor(acc, off);
        if (lane == 0) {
          int s = q * 32 + sl;
          sc[sl] = (s < vl) ? __expf(acc) : 0.f;  // no-max softmax: |score|<=~9
        }
      }
      __syncthreads();
      if (tid < 32) {
        float p2 = sc[tid];
#pragma unroll
        for (int off = 1; off < 32; off <<= 1) p2 += __shfl_xor(p2, off, 32);
        if (tid == 0) atomicAdd(&den[b], p2);
      }
      if (tid < 512) {
        float acc = 0.f;
#pragma unroll 8
        for (int s = 0; s < 32; s++) acc += sc[s] * bf2f(encL[s * 512 + tid]);
        atomicAdd(&ctxT[q4(tid, b)], acc);
      }
    }
    gbar(arrive, go, ++ep, blk, tid);

    // ---- P2: GRU cell 0 ----
    cell_phase<true>(blk, tid, t, ctxT, embTf, h0prev, wLDS + W0IH, wLDS + W0HH,
                     bih0, bhh0, den, h0next, nullptr, scratch);
    gbar(arrive, go, ++ep, blk, tid);

    // ---- P3: zero ctxT/den + GRU cell 1 ----
    if (tid < 128) st_llc(&ctxT[blk * 128 + tid], 0.f);
    if (blk < Bd && tid == 128) st_llc(&den[blk], 0.f);
    cell_phase<false>(blk, tid, t, h0next, nullptr, h1prev, wLDS + W1IH,
                      wLDS + W1HH, bih1, bhh1, nullptr, h1next, ysbf, scratch);
    gbar(arrive, go, ++ep, blk, tid);
  }
}

extern "C" void kernel_launch(void* const* d_in, const int* in_sizes, int n_in,
                              void* d_out, int out_size, void* d_ws, size_t ws_size,
                              hipStream_t stream) {
  const int* x = (const int*)d_in[0];
  const float* enc = (const float*)d_in[1];
  const float* h0 = (const float*)d_in[2];
  const int* vlen = (const int*)d_in[3];
  const float* emb = (const float*)d_in[4];
  const float* Wq = (const float*)d_in[5];
  const float* Wk = (const float*)d_in[6];
  const float* wv = (const float*)d_in[7];
  const float* W_ih0 = (const float*)d_in[8];
  const float* W_hh0 = (const float*)d_in[9];
  const float* b_ih0 = (const float*)d_in[10];
  const float* b_hh0 = (const float*)d_in[11];
  const float* W_ih1 = (const float*)d_in[12];
  const float* W_hh1 = (const float*)d_in[13];
  const float* b_ih1 = (const float*)d_in[14];
  const float* b_hh1 = (const float*)d_in[15];
  const float* Wd = (const float*)d_in[16];
  const float* bd = (const float*)d_in[17];
  float* out = (float*)d_out;

  char* p = (char*)d_ws;
  int* bar = (int*)p;
  p += 2048;
  unsigned short* kpbf = (unsigned short*)p;   // B*S*H bf16
  p += (size_t)Bd * Sd * Hd * 2;
  unsigned short* encbf = (unsigned short*)p;  // B*S*H bf16
  p += (size_t)Bd * Sd * Hd * 2;
  unsigned short* Wdbf = (unsigned short*)p;   // V*H bf16
  p += (size_t)Vd * Hd * 2;
  unsigned short* ysbf = (unsigned short*)p;   // T*B*H bf16
  p += (size_t)Td * Bd * Hd * 2;
  float* embTf = (float*)p;  // T*E*B f32 (k-quad)
  p += (size_t)Td * Ed * Bd * 4;
  float* qpN = (float*)p;   p += (size_t)Bd * Hd * 4;
  float* ctxT = (float*)p;  p += (size_t)Hd * Bd * 4;
  float* den = (float*)p;   p += 256;
  float* h0TA = (float*)p;  p += (size_t)Hd * Bd * 4;
  float* h0TB = (float*)p;  p += (size_t)Hd * Bd * 4;
  float* h1TA = (float*)p;  p += (size_t)Hd * Bd * 4;
  float* h1TB = (float*)p;

  hipMemsetAsync(bar, 0, 2048, stream);

  // kp = enc @ Wk^T -> bf16
  k_gemm_kp<<<dim3(128, 8), 256, 0, stream>>>(enc, Wk, kpbf, Bd * Sd, Hd, Hd);
  // enc, Wd -> bf16
  long nenc = (long)Bd * Sd * Hd;
  k_tobf<<<(nenc + 1023) / 1024, 1024, 0, stream>>>(enc, encbf, nenc);
  long nwd = (long)Vd * Hd;
  k_tobf<<<(nwd + 1023) / 1024, 1024, 0, stream>>>(Wd, Wdbf, nwd);
  // embTf gather+transpose (f32, k-quad)
  k_embT<<<Td, 256, 0, stream>>>(x, emb, embTf);
  // fused 64-step decoder (4 barriers/step)
  k_decoder<<<NBLK, 1024, 0, stream>>>(h0, vlen, Wq, wv, W_ih0, W_hh0, b_ih0,
                                       b_hh0, W_ih1, W_hh1, b_ih1, b_hh1, kpbf,
                                       encbf, embTf, bar, qpN, ctxT, den, h0TA,
                                       h0TB, h1TA, h1TB, ysbf);
  // logits: bf16 MFMA GEMM
  k_logits<<<dim3(64, 157), 256, 0, stream>>>(ysbf, Wdbf, bd, out, Vd);
}